// Round 1
// baseline (7699.772 us; speedup 1.0000x reference)
//
#include <hip/hip_runtime.h>

#define T_STEPS 101
#define BATCH   16384
#define IN_DIM  40
#define HID     300
#define OUT_DIM 12

#define RPW 2             // rows per wave (was 8: VGPR demand ~225 -> spilled at the 256 cap)
#define WPB 8             // waves per block (512 threads)
#define RPB (RPW * WPB)   // 16 rows per block
#define NTHREADS (WPB * 64)

// ---- ws layout (floats) ----
// [0, 96000)         WhT[i][j] = Wh[j][i], column stride 320 (j in [300,320) = 0)
// [96000, 192000)    W2T[i][j] = W2[j][i], column stride 320
// [192000, 195600)   W3T[i][o] = W3[o][i], stride 12
#define WS_W2T 96000
#define WS_W3T 192000

// compile-time unroll helper: guarantees constexpr indices even when the
// loop body contains data-dependent while-loops (plain #pragma unroll bails
// -> dynamic alloca -> scratch traffic).
template<int I> struct ic { static constexpr int v = I; };
template<int N, int I = 0, typename F>
__device__ __forceinline__ void sfor(F&& f) {
    if constexpr (I < N) {
        f(ic<I>{});
        sfor<N, I + 1, F>(static_cast<F&&>(f));
    }
}

__global__ __launch_bounds__(256) void prep_kernel(const float* __restrict__ Wh,
                                                   const float* __restrict__ W2,
                                                   const float* __restrict__ W3,
                                                   float* __restrict__ ws) {
    int idx = blockIdx.x * 256 + threadIdx.x;
    if (idx < 96000) {
        int i = idx / 320, j = idx % 320;
        ws[idx] = (j < HID) ? Wh[j * HID + i] : 0.f;
    } else if (idx < 192000) {
        int k = idx - 96000;
        int i = k / 320, j = k % 320;
        ws[idx] = (j < HID) ? W2[j * HID + i] : 0.f;
    } else if (idx < 195600) {
        int k = idx - 192000;
        int i = k / OUT_DIM, j = k % OUT_DIM;
        ws[idx] = W3[j * HID + i];
    }
}

// Two-row interleaved sparse-column gather.
// FP-exactness contract: for each row, columns are added in ascending j order
// (same as the dense ascending dot, so skipped zero terms change nothing).
// fmaf(1.0f, w, a) rounds identically to a + w; empty-row iterations use
// g = 0.0f with a clamped (finite) dummy column, which leaves a unchanged.
// Both masks are wave-uniform (from __ballot) -> SALU control flow; the 10
// loads issue before any wait -> MLP 10 instead of 5.
__device__ __forceinline__ void walk2(const float* __restrict__ base, // tab + u2*64*320 + lane
                                      unsigned long long m0, unsigned long long m1,
                                      float (&a0)[5], float (&a1)[5]) {
    while (m0 | m1) {
        const bool h0 = (m0 != 0ull), h1 = (m1 != 0ull);
        const int b0 = h0 ? (int)__builtin_ctzll(m0) : 0;   // clamp: dummy col is in-range/finite
        const int b1 = h1 ? (int)__builtin_ctzll(m1) : 0;
        m0 &= m0 - 1;   // 0-safe: 0 & ~0 == 0
        m1 &= m1 - 1;
        const float g0 = h0 ? 1.0f : 0.0f;
        const float g1 = h1 ? 1.0f : 0.0f;
        const float* p0 = base + b0 * 320;
        const float* p1 = base + b1 * 320;
        float l0[5], l1[5];
        sfor<5>([&](auto uc) { constexpr int u = decltype(uc)::v; l0[u] = p0[64 * u]; });
        sfor<5>([&](auto uc) { constexpr int u = decltype(uc)::v; l1[u] = p1[64 * u]; });
        sfor<5>([&](auto uc) { constexpr int u = decltype(uc)::v; a0[u] = fmaf(g0, l0[u], a0[u]); });
        sfor<5>([&](auto uc) { constexpr int u = decltype(uc)::v; a1[u] = fmaf(g1, l1[u], a1[u]); });
    }
}

// launch_bounds(512, 4): cap VGPRs at 128 -> 4 waves/SIMD, 2 blocks/CU
// (LDS ~52 KB/block -> 104 KB resident). RPW=2 demand is ~80 VGPRs, so the
// cap does NOT force spills (round-2 lesson applied at the right row count).
__global__ __launch_bounds__(NTHREADS, 4) void snn_kernel(
    const float* __restrict__ x,    // [T, B, 40]
    const float* __restrict__ W1,   // [300, 40]
    const float* __restrict__ b1,   // [300]
    const float* __restrict__ bh,   // [300]
    const float* __restrict__ b2,   // [300]
    const float* __restrict__ b3,   // [12]
    const float* __restrict__ ws,   // transposed/padded weights
    float* __restrict__ out)        // [B, 12]
{
    // w1c[kc][j][c] = W1[j][4*kc+c], j padded to 320 (zeros). Lane reads
    // float4 at (kc*320 + j)*4 -> 16B stride across lanes: conflict-free.
    __shared__ float w1c[10 * 320 * 4];                 // 51200 B
    __shared__ float oacc[RPB][OUT_DIM];

    const int tid  = threadIdx.x;
    const int lane = tid & 63;
    const int wv   = __builtin_amdgcn_readfirstlane(tid >> 6);  // wave-uniform
    const int row0 = blockIdx.x * RPB;

    // ---- stage W1 into chunked LDS layout ----
    for (int idx = tid; idx < 3200; idx += NTHREADS) {
        int kc = idx % 10;
        int j  = idx / 10;
        float4 v;
        if (j < HID) v = *(const float4*)(W1 + j * IN_DIM + kc * 4);
        else         v = make_float4(0.f, 0.f, 0.f, 0.f);
        *(float4*)(w1c + (kc * 320 + j) * 4) = v;
    }
    for (int idx = tid; idx < RPB * OUT_DIM; idx += NTHREADS) ((float*)oacc)[idx] = 0.f;

    // per-lane biases for neurons j = lane + 64u (tail j>=300 -> 0)
    float b1h[5], b2r[5];
    sfor<5>([&](auto uc) {
        constexpr int u = decltype(uc)::v;
        int j = lane + 64 * u;
        b1h[u] = (j < HID) ? (b1[j] + bh[j]) : 0.f;
        b2r[u] = (j < HID) ? b2[j] : 0.f;
    });

    const float* WhT = ws;
    const float* W2T = ws + WS_W2T;
    const float* W3T = ws + WS_W3T;

    float v1[RPW][5], v2[RPW][5];
    // prev-step layer-1 spike masks, wave-private and wave-uniform -> SGPRs.
    // (old kernel round-tripped these through LDS; at RPW=2 they fit in 20 SGPRs)
    unsigned long long pm[RPW][5];
    sfor<RPW>([&](auto rc) {
        constexpr int r = decltype(rc)::v;
        sfor<5>([&](auto uc) {
            constexpr int u = decltype(uc)::v;
            v1[r][u] = 0.f; v2[r][u] = 0.f; pm[r][u] = 0ull;
        });
    });

    __syncthreads();

    const unsigned long long TAILMASK = (1ull << 44) - 1ull;  // 44 valid lanes at u=4

    for (int t = 0; t < T_STEPS; ++t) {
        // wave-uniform base for this wave's 2 rows at step t -> s_load path
        const float* xt = x + ((size_t)t * BATCH + row0 + wv * RPW) * IN_DIM;

        // ---- Phase A: h1 = x @ W1^T + (b1 + bh) ----
        float acc[RPW][5];
        sfor<RPW>([&](auto rc) {
            constexpr int r = decltype(rc)::v;
            sfor<5>([&](auto uc) {
                constexpr int u = decltype(uc)::v;
                acc[r][u] = b1h[u];
            });
        });

        sfor<10>([&](auto kcc) {
            constexpr int kc = decltype(kcc)::v;
            float4 w[5];
            sfor<5>([&](auto uc) {
                constexpr int u = decltype(uc)::v;
                w[u] = *(const float4*)(w1c + (kc * 320 + lane + 64 * u) * 4);
            });
            sfor<RPW>([&](auto rc) {
                constexpr int r = decltype(rc)::v;
                const float* xr = xt + r * IN_DIM + kc * 4;   // uniform
                float x0 = xr[0], x1 = xr[1], x2 = xr[2], x3 = xr[3];
                sfor<5>([&](auto uc) {
                    constexpr int u = decltype(uc)::v;
                    float a = acc[r][u];
                    a = fmaf(w[u].x, x0, a);
                    a = fmaf(w[u].y, x1, a);
                    a = fmaf(w[u].z, x2, a);
                    a = fmaf(w[u].w, x3, a);
                    acc[r][u] = a;
                });
            });
        });

        // ---- Phase B: recurrent input y_{t-1} @ Wh^T, 2 rows interleaved ----
        sfor<5>([&](auto u2c) {
            constexpr int u2 = decltype(u2c)::v;
            walk2(WhT + u2 * 64 * 320 + lane, pm[0][u2], pm[1][u2], acc[0], acc[1]);
        });

        // ---- Phase C: LIF layer 1 (v += (cur-v)/2 ; spike ; hard reset) ----
        unsigned long long nm[RPW][5];
        sfor<RPW>([&](auto rc) {
            constexpr int r = decltype(rc)::v;
            sfor<5>([&](auto uc) {
                constexpr int u = decltype(uc)::v;
                float v = v1[r][u];
                v = v + (acc[r][u] - v) * 0.5f;
                bool s = (v >= 1.0f);
                v1[r][u] = s ? 0.f : v;
                nm[r][u] = __ballot(s);
            });
            nm[r][4] &= TAILMASK;
            sfor<5>([&](auto uc) {
                constexpr int u = decltype(uc)::v;
                pm[r][u] = nm[r][u];     // feed next step's recurrence
            });
        });

        // ---- Phase D: cur2 = y @ W2^T + b2, 2 rows interleaved ----
        float c2[RPW][5];
        sfor<RPW>([&](auto rc) {
            constexpr int r = decltype(rc)::v;
            sfor<5>([&](auto uc) {
                constexpr int u = decltype(uc)::v;
                c2[r][u] = b2r[u];
            });
        });
        sfor<5>([&](auto u2c) {
            constexpr int u2 = decltype(u2c)::v;
            walk2(W2T + u2 * 64 * 320 + lane, nm[0][u2], nm[1][u2], c2[0], c2[1]);
        });

        // ---- Phase E/F: LIF layer 2 + output accumulation (s2 rare) ----
        sfor<RPW>([&](auto rc) {
            constexpr int r = decltype(rc)::v;
            unsigned long long sm[5];
            sfor<5>([&](auto uc) {
                constexpr int u = decltype(uc)::v;
                float v = v2[r][u];
                v = v + (c2[r][u] - v) * 0.5f;
                bool s = (v >= 1.0f);
                v2[r][u] = s ? 0.f : v;
                sm[u] = __ballot(s);
            });
            sm[4] &= TAILMASK;
            const int lr = wv * RPW + r;
            sfor<5>([&](auto u2c) {
                constexpr int u2 = decltype(u2c)::v;
                unsigned long long m = sm[u2];
                while (m) {
                    int b = __builtin_ctzll(m);
                    m &= m - 1;
                    if (lane < OUT_DIM)
                        oacc[lr][lane] += W3T[(u2 * 64 + b) * OUT_DIM + lane];
                }
            });
        });
    }

    __syncthreads();

    // ---- epilogue: out = oacc + 101 * b3 ----
    for (int idx = tid; idx < RPB * OUT_DIM; idx += NTHREADS) {
        int r = idx / OUT_DIM, o = idx % OUT_DIM;
        out[(size_t)(row0 + r) * OUT_DIM + o] = oacc[r][o] + 101.0f * b3[o];
    }
}

extern "C" void kernel_launch(void* const* d_in, const int* in_sizes, int n_in,
                              void* d_out, int out_size, void* d_ws, size_t ws_size,
                              hipStream_t stream) {
    const float* x  = (const float*)d_in[0];
    const float* W1 = (const float*)d_in[1];
    const float* b1 = (const float*)d_in[2];
    const float* Wh = (const float*)d_in[3];
    const float* bh = (const float*)d_in[4];
    const float* W2 = (const float*)d_in[5];
    const float* b2 = (const float*)d_in[6];
    const float* W3 = (const float*)d_in[7];
    const float* b3 = (const float*)d_in[8];
    float* out = (float*)d_out;
    float* ws  = (float*)d_ws;

    prep_kernel<<<(195600 + 255) / 256, 256, 0, stream>>>(Wh, W2, W3, ws);
    snn_kernel<<<BATCH / RPB, NTHREADS, 0, stream>>>(x, W1, b1, bh, b2, b3, ws, out);
}

// Round 2
// 2805.705 us; speedup vs baseline: 2.7443x; 2.7443x over previous
//
#include <hip/hip_runtime.h>

#define T_STEPS 101
#define BATCH   16384
#define IN_DIM  40
#define HID     300
#define OUT_DIM 12

#define RPW 4             // rows per wave: amortizes W1 LDS reads 4x; walk MLP = 20
#define WPB 8             // waves per block (512 threads)
#define RPB (RPW * WPB)   // 32 rows per block
#define NTHREADS (WPB * 64)

// ---- ws layout (floats) ----
// [0, 96000)         WhT[i][j] = Wh[j][i], column stride 320 (j in [300,320) = 0)
// [96000, 192000)    W2T[i][j] = W2[j][i], column stride 320
// [192000, 195600)   W3T[i][o] = W3[o][i], stride 12
#define WS_W2T 96000
#define WS_W3T 192000

// compile-time unroll helper: guarantees constexpr indices even when the
// loop body contains data-dependent while-loops (plain #pragma unroll bails
// -> dynamic alloca -> scratch traffic).
template<int I> struct ic { static constexpr int v = I; };
template<int N, int I = 0, typename F>
__device__ __forceinline__ void sfor(F&& f) {
    if constexpr (I < N) {
        f(ic<I>{});
        sfor<N, I + 1, F>(static_cast<F&&>(f));
    }
}

__global__ __launch_bounds__(256) void prep_kernel(const float* __restrict__ Wh,
                                                   const float* __restrict__ W2,
                                                   const float* __restrict__ W3,
                                                   float* __restrict__ ws) {
    int idx = blockIdx.x * 256 + threadIdx.x;
    if (idx < 96000) {
        int i = idx / 320, j = idx % 320;
        ws[idx] = (j < HID) ? Wh[j * HID + i] : 0.f;
    } else if (idx < 192000) {
        int k = idx - 96000;
        int i = k / 320, j = k % 320;
        ws[idx] = (j < HID) ? W2[j * HID + i] : 0.f;
    } else if (idx < 195600) {
        int k = idx - 192000;
        int i = k / OUT_DIM, j = k % OUT_DIM;
        ws[idx] = W3[j * HID + i];
    }
}

// Four-row interleaved sparse-column gather.
// FP-exactness contract: for each row, columns are added in ascending j order
// (same as the dense ascending dot, so skipped zero terms change nothing).
// fmaf(1.0f, w, a) rounds identically to a + w; rows whose mask is exhausted
// use g = 0.0f with a clamped (finite, in-range) dummy column -> a unchanged.
// Masks are wave-uniform (__ballot) -> SALU control flow; 20 loads issue
// before any wait -> MLP 20; chain length per u2-chunk = max(n0..n3).
__device__ __forceinline__ void walk4(const float* __restrict__ base, // tab + u2*64*320 + lane
                                      unsigned long long m0, unsigned long long m1,
                                      unsigned long long m2, unsigned long long m3,
                                      float (&a0)[5], float (&a1)[5],
                                      float (&a2)[5], float (&a3)[5]) {
    while (m0 | m1 | m2 | m3) {
        const bool h0 = (m0 != 0ull), h1 = (m1 != 0ull), h2 = (m2 != 0ull), h3 = (m3 != 0ull);
        const int b0 = h0 ? (int)__builtin_ctzll(m0) : 0;
        const int b1 = h1 ? (int)__builtin_ctzll(m1) : 0;
        const int b2 = h2 ? (int)__builtin_ctzll(m2) : 0;
        const int b3 = h3 ? (int)__builtin_ctzll(m3) : 0;
        m0 &= m0 - 1; m1 &= m1 - 1; m2 &= m2 - 1; m3 &= m3 - 1;   // 0-safe
        const float g0 = h0 ? 1.0f : 0.0f;
        const float g1 = h1 ? 1.0f : 0.0f;
        const float g2 = h2 ? 1.0f : 0.0f;
        const float g3 = h3 ? 1.0f : 0.0f;
        const float* p0 = base + b0 * 320;
        const float* p1 = base + b1 * 320;
        const float* p2 = base + b2 * 320;
        const float* p3 = base + b3 * 320;
        float l0[5], l1[5], l2[5], l3[5];
        sfor<5>([&](auto uc) { constexpr int u = decltype(uc)::v; l0[u] = p0[64 * u]; });
        sfor<5>([&](auto uc) { constexpr int u = decltype(uc)::v; l1[u] = p1[64 * u]; });
        sfor<5>([&](auto uc) { constexpr int u = decltype(uc)::v; l2[u] = p2[64 * u]; });
        sfor<5>([&](auto uc) { constexpr int u = decltype(uc)::v; l3[u] = p3[64 * u]; });
        sfor<5>([&](auto uc) { constexpr int u = decltype(uc)::v; a0[u] = fmaf(g0, l0[u], a0[u]); });
        sfor<5>([&](auto uc) { constexpr int u = decltype(uc)::v; a1[u] = fmaf(g1, l1[u], a1[u]); });
        sfor<5>([&](auto uc) { constexpr int u = decltype(uc)::v; a2[u] = fmaf(g2, l2[u], a2[u]); });
        sfor<5>([&](auto uc) { constexpr int u = decltype(uc)::v; a3[u] = fmaf(g3, l3[u], a3[u]); });
    }
}

// __launch_bounds__(512, 2): round-1 post-mortem — hipcc treats the 2nd arg as
// min WORKGROUPS/CU: (512,4) meant 32 waves/CU -> 8 waves/SIMD -> 64-VGPR cap
// against ~100-reg demand -> forced spill -> 25 GB of scratch HBM traffic.
// (512,2) = 16 waves/CU = 4 waves/SIMD -> cap 128 >= demand (~110): no spill
// under EITHER interpretation of the argument. Grid is exactly 2 blocks/CU.
__global__ __launch_bounds__(NTHREADS, 2) void snn_kernel(
    const float* __restrict__ x,    // [T, B, 40]
    const float* __restrict__ W1,   // [300, 40]
    const float* __restrict__ b1,   // [300]
    const float* __restrict__ bh,   // [300]
    const float* __restrict__ b2,   // [300]
    const float* __restrict__ b3,   // [12]
    const float* __restrict__ ws,   // transposed/padded weights
    float* __restrict__ out)        // [B, 12]
{
    // w1c[kc][j][c] = W1[j][4*kc+c], j padded to 320 (zeros). Lane reads
    // float4 at (kc*320 + j)*4 -> 16B stride across lanes: conflict-free.
    __shared__ float w1c[10 * 320 * 4];                 // 51200 B
    __shared__ float oacc[RPB][OUT_DIM];

    const int tid  = threadIdx.x;
    const int lane = tid & 63;
    const int wv   = __builtin_amdgcn_readfirstlane(tid >> 6);  // wave-uniform
    const int row0 = blockIdx.x * RPB;

    // ---- stage W1 into chunked LDS layout ----
    for (int idx = tid; idx < 3200; idx += NTHREADS) {
        int kc = idx % 10;
        int j  = idx / 10;
        float4 v;
        if (j < HID) v = *(const float4*)(W1 + j * IN_DIM + kc * 4);
        else         v = make_float4(0.f, 0.f, 0.f, 0.f);
        *(float4*)(w1c + (kc * 320 + j) * 4) = v;
    }
    for (int idx = tid; idx < RPB * OUT_DIM; idx += NTHREADS) ((float*)oacc)[idx] = 0.f;

    // per-lane biases for neurons j = lane + 64u (tail j>=300 -> 0)
    float b1h[5], b2r[5];
    sfor<5>([&](auto uc) {
        constexpr int u = decltype(uc)::v;
        int j = lane + 64 * u;
        b1h[u] = (j < HID) ? (b1[j] + bh[j]) : 0.f;
        b2r[u] = (j < HID) ? b2[j] : 0.f;
    });

    const float* WhT = ws;
    const float* W2T = ws + WS_W2T;
    const float* W3T = ws + WS_W3T;

    float v1[RPW][5], v2[RPW][5];
    // layer-1 spike masks: wave-uniform (__ballot) -> live in SGPRs. Written
    // in Phase C (current y), read in Phase D (y @ W2^T) and next-t Phase B
    // (y_{t-1} @ Wh^T) — single storage, no LDS round-trip.
    unsigned long long pm[RPW][5];
    sfor<RPW>([&](auto rc) {
        constexpr int r = decltype(rc)::v;
        sfor<5>([&](auto uc) {
            constexpr int u = decltype(uc)::v;
            v1[r][u] = 0.f; v2[r][u] = 0.f; pm[r][u] = 0ull;
        });
    });

    __syncthreads();

    const unsigned long long TAILMASK = (1ull << 44) - 1ull;  // 44 valid lanes at u=4

    for (int t = 0; t < T_STEPS; ++t) {
        // wave-uniform base for this wave's 4 rows at step t -> s_load path
        const float* xt = x + ((size_t)t * BATCH + row0 + wv * RPW) * IN_DIM;

        // ---- Phase A: h1 = x @ W1^T + (b1 + bh) ----
        float acc[RPW][5];
        sfor<RPW>([&](auto rc) {
            constexpr int r = decltype(rc)::v;
            sfor<5>([&](auto uc) {
                constexpr int u = decltype(uc)::v;
                acc[r][u] = b1h[u];
            });
        });

        sfor<10>([&](auto kcc) {
            constexpr int kc = decltype(kcc)::v;
            float4 w[5];
            sfor<5>([&](auto uc) {
                constexpr int u = decltype(uc)::v;
                w[u] = *(const float4*)(w1c + (kc * 320 + lane + 64 * u) * 4);
            });
            sfor<RPW>([&](auto rc) {
                constexpr int r = decltype(rc)::v;
                const float* xr = xt + r * IN_DIM + kc * 4;   // uniform -> s_load
                float x0 = xr[0], x1 = xr[1], x2 = xr[2], x3 = xr[3];
                sfor<5>([&](auto uc) {
                    constexpr int u = decltype(uc)::v;
                    float a = acc[r][u];
                    a = fmaf(w[u].x, x0, a);
                    a = fmaf(w[u].y, x1, a);
                    a = fmaf(w[u].z, x2, a);
                    a = fmaf(w[u].w, x3, a);
                    acc[r][u] = a;
                });
            });
        });

        // ---- Phase B: recurrent input y_{t-1} @ Wh^T, 4 rows interleaved ----
        sfor<5>([&](auto u2c) {
            constexpr int u2 = decltype(u2c)::v;
            walk4(WhT + u2 * 64 * 320 + lane,
                  pm[0][u2], pm[1][u2], pm[2][u2], pm[3][u2],
                  acc[0], acc[1], acc[2], acc[3]);
        });

        // ---- Phase C: LIF layer 1 (v += (cur-v)/2 ; spike ; hard reset) ----
        sfor<RPW>([&](auto rc) {
            constexpr int r = decltype(rc)::v;
            sfor<5>([&](auto uc) {
                constexpr int u = decltype(uc)::v;
                float v = v1[r][u];
                v = v + (acc[r][u] - v) * 0.5f;
                bool s = (v >= 1.0f);
                v1[r][u] = s ? 0.f : v;
                pm[r][u] = __ballot(s);   // current y: used by D and next-t B
            });
            pm[r][4] &= TAILMASK;
        });

        // ---- Phase D: cur2 = y @ W2^T + b2, 4 rows interleaved ----
        float c2[RPW][5];
        sfor<RPW>([&](auto rc) {
            constexpr int r = decltype(rc)::v;
            sfor<5>([&](auto uc) {
                constexpr int u = decltype(uc)::v;
                c2[r][u] = b2r[u];
            });
        });
        sfor<5>([&](auto u2c) {
            constexpr int u2 = decltype(u2c)::v;
            walk4(W2T + u2 * 64 * 320 + lane,
                  pm[0][u2], pm[1][u2], pm[2][u2], pm[3][u2],
                  c2[0], c2[1], c2[2], c2[3]);
        });

        // ---- Phase E: LIF layer 2 + output accumulation (s2 spikes rare) ----
        sfor<RPW>([&](auto rc) {
            constexpr int r = decltype(rc)::v;
            unsigned long long sm[5];
            sfor<5>([&](auto uc) {
                constexpr int u = decltype(uc)::v;
                float v = v2[r][u];
                v = v + (c2[r][u] - v) * 0.5f;
                bool s = (v >= 1.0f);
                v2[r][u] = s ? 0.f : v;
                sm[u] = __ballot(s);
            });
            sm[4] &= TAILMASK;
            const int lr = wv * RPW + r;
            sfor<5>([&](auto u2c) {
                constexpr int u2 = decltype(u2c)::v;
                unsigned long long m = sm[u2];
                while (m) {
                    int b = __builtin_ctzll(m);
                    m &= m - 1;
                    if (lane < OUT_DIM)
                        oacc[lr][lane] += W3T[(u2 * 64 + b) * OUT_DIM + lane];
                }
            });
        });
    }

    __syncthreads();

    // ---- epilogue: out = oacc + 101 * b3 ----
    for (int idx = tid; idx < RPB * OUT_DIM; idx += NTHREADS) {
        int r = idx / OUT_DIM, o = idx % OUT_DIM;
        out[(size_t)(row0 + r) * OUT_DIM + o] = oacc[r][o] + 101.0f * b3[o];
    }
}

extern "C" void kernel_launch(void* const* d_in, const int* in_sizes, int n_in,
                              void* d_out, int out_size, void* d_ws, size_t ws_size,
                              hipStream_t stream) {
    const float* x  = (const float*)d_in[0];
    const float* W1 = (const float*)d_in[1];
    const float* b1 = (const float*)d_in[2];
    const float* Wh = (const float*)d_in[3];
    const float* bh = (const float*)d_in[4];
    const float* W2 = (const float*)d_in[5];
    const float* b2 = (const float*)d_in[6];
    const float* W3 = (const float*)d_in[7];
    const float* b3 = (const float*)d_in[8];
    float* out = (float*)d_out;
    float* ws  = (float*)d_ws;

    prep_kernel<<<(195600 + 255) / 256, 256, 0, stream>>>(Wh, W2, W3, ws);
    snn_kernel<<<BATCH / RPB, NTHREADS, 0, stream>>>(x, W1, b1, bh, b2, b3, ws, out);
}